// Round 14
// baseline (177.106 us; speedup 1.0000x reference)
//
#include <hip/hip_runtime.h>

#define NN 50000
#define NNP 50048   // Ab rows padded: 50048 = 128 * 391 (gemm block = 128 rows)
#define NE 640000
#define IC 128
#define HC 256
#define OC 3
#define PAD 64      // padded CSR row capacity; P(deg>=64)~1e-25 for Poisson(12.8); guarded anyway

#define TOBF16_BLOCKS (NN * IC / 4 / 256)          // 6250
#define WPACK_BLOCKS  32
#define DEGZ_BLOCKS   ((NN * 16 / 4 + 255) / 256)  // 782: zero NN*16 ints as uint4

typedef __attribute__((ext_vector_type(8))) short short8;
typedef __attribute__((ext_vector_type(4))) float f32x4;

__device__ __forceinline__ unsigned short f2bf(float f) {   // fp32 -> bf16 RNE
    unsigned int u = __float_as_uint(f);
    unsigned int r = u + 0x7FFFu + ((u >> 16) & 1u);
    return (unsigned short)(r >> 16);
}
__device__ __forceinline__ float bflo(unsigned int v) { return __uint_as_float(v << 16); }
__device__ __forceinline__ float bfhi(unsigned int v) { return __uint_as_float(v & 0xffff0000u); }

// ---------------- prep: zero spread-degi | x->bf16 | pack W ----------------
__global__ __launch_bounds__(256) void k_prep(const float* __restrict__ x,
                                              const float* __restrict__ Wl0,
                                              const float* __restrict__ Wr0,
                                              unsigned short* __restrict__ Ab,
                                              unsigned short* __restrict__ Bp,
                                              int* __restrict__ degi) {
    int b = blockIdx.x;
    int t = threadIdx.x;
    if (b < TOBF16_BLOCKS) {
        // x -> bf16 into right half of Ab (Ab: ushort[NNP][256], cols 128..255 = x)
        int i = b * 256 + t;                  // over NN*IC/4 float4s
        int n = i >> 5;
        int c = (i & 31) * 4;
        float4 v = ((const float4*)x)[i];
        ushort4 o;
        o.x = f2bf(v.x); o.y = f2bf(v.y); o.z = f2bf(v.z); o.w = f2bf(v.w);
        *(ushort4*)&Ab[(size_t)n * 256 + 128 + c] = o;
    } else if (b < TOBF16_BLOCKS + WPACK_BLOCKS) {
        // pack [Wl0;Wr0] into MFMA B-fragment order:
        // Bp[kt(8)][nt(16)][lane(64)][e(8)], B[k][n]: k=kt*32+(lane>>4)*8+e, n=nt*16+(lane&15)
        int tt = (b - TOBF16_BLOCKS) * 256 + t;     // 8192 threads
        int l = tt & 63;
        int nt = (tt >> 6) & 15;
        int kt = tt >> 10;
        int n = nt * 16 + (l & 15);
        int kbase = kt * 32 + (l >> 4) * 8;
        unsigned short o[8];
        #pragma unroll
        for (int e = 0; e < 8; ++e) {
            int k = kbase + e;
            float w = (k < IC) ? Wl0[k * HC + n] : Wr0[(k - IC) * HC + n];
            o[e] = f2bf(w);
        }
        #pragma unroll
        for (int e = 0; e < 8; ++e) Bp[(size_t)tt * 8 + e] = o[e];
    } else {
        // zero spread degi: counter n lives at degi[n*16] (one per 64B line)
        int idx = (b - TOBF16_BLOCKS - WPACK_BLOCKS) * 256 + t;
        if (idx < NN * 16 / 4) ((uint4*)degi)[idx] = make_uint4(0u, 0u, 0u, 0u);
    }
}

// ---------------- one-pass padded-CSR build; line-isolated counters ----------------
__global__ __launch_bounds__(256) void k_build(const int* __restrict__ ei,
                                               int* __restrict__ degi,
                                               unsigned short* __restrict__ csrp) {
    int e = blockIdx.x * blockDim.x + threadIdx.x;
    if (e >= NE) return;
    int src = ei[e];
    int dst = ei[NE + e];
    int rank = atomicAdd(&degi[dst << 4], 1);   // stride-16: one counter per cache line
    if (rank < PAD) csrp[dst * PAD + rank] = (unsigned short)src;
}

// ---------------- gather-mean: 8 edge-subgroups x 8 lanes x 2 uint4 (32B/lane) ----------------
__global__ __launch_bounds__(256) void k_agg(const int* __restrict__ degi,
                                             const unsigned short* __restrict__ csrp,
                                             unsigned short* __restrict__ Ab) {
    int wid = (blockIdx.x * blockDim.x + threadIdx.x) >> 6;
    int lane = threadIdx.x & 63;
    if (wid >= NN) return;
    int deg = min(degi[wid << 4], PAD);
    int beg = wid * PAD;
    int sg = lane >> 3;        // edge subgroup 0..7 (8 edges in flight per wave)
    int s  = lane & 7;         // this lane covers uint4 slots s and s+8 of the x-half
    const uint4* base = (const uint4*)Ab;     // 32 uint4 per 512B row

    float a[16];
    #pragma unroll
    for (int i = 0; i < 16; ++i) a[i] = 0.f;

    for (int j = sg; j < deg; j += 8) {
        int src = csrp[beg + j];
        uint4 v0 = base[(size_t)src * 32 + 16 + s];
        uint4 v1 = base[(size_t)src * 32 + 24 + s];
        a[0] += bflo(v0.x); a[1] += bfhi(v0.x);
        a[2] += bflo(v0.y); a[3] += bfhi(v0.y);
        a[4] += bflo(v0.z); a[5] += bfhi(v0.z);
        a[6] += bflo(v0.w); a[7] += bfhi(v0.w);
        a[8]  += bflo(v1.x); a[9]  += bfhi(v1.x);
        a[10] += bflo(v1.y); a[11] += bfhi(v1.y);
        a[12] += bflo(v1.z); a[13] += bfhi(v1.z);
        a[14] += bflo(v1.w); a[15] += bfhi(v1.w);
    }
    #pragma unroll
    for (int m = 8; m <= 32; m <<= 1)
        #pragma unroll
        for (int i = 0; i < 16; ++i) a[i] += __shfl_xor(a[i], m);

    if (sg == 0) {
        float inv = 1.0f / fmaxf((float)deg, 1.0f);
        uint4 o0, o1;
        o0.x = ((unsigned int)f2bf(a[1] * inv) << 16) | f2bf(a[0] * inv);
        o0.y = ((unsigned int)f2bf(a[3] * inv) << 16) | f2bf(a[2] * inv);
        o0.z = ((unsigned int)f2bf(a[5] * inv) << 16) | f2bf(a[4] * inv);
        o0.w = ((unsigned int)f2bf(a[7] * inv) << 16) | f2bf(a[6] * inv);
        o1.x = ((unsigned int)f2bf(a[9]  * inv) << 16) | f2bf(a[8]  * inv);
        o1.y = ((unsigned int)f2bf(a[11] * inv) << 16) | f2bf(a[10] * inv);
        o1.z = ((unsigned int)f2bf(a[13] * inv) << 16) | f2bf(a[12] * inv);
        o1.w = ((unsigned int)f2bf(a[15] * inv) << 16) | f2bf(a[14] * inv);
        ((uint4*)Ab)[(size_t)wid * 32 + s] = o0;
        ((uint4*)Ab)[(size_t)wid * 32 + 8 + s] = o1;
    }
}

// ---------------- MFMA GEMM v4: 2 row-tiles per wave (B-fragment reuse x2) ----------------
// block = 4 waves x 128 rows; each B fragment read from LDS feeds 2 MFMAs.
// H = relu(Ab @ [Wl0;Wr0] + bl0); g = H@Wl1; r = H@Wr1
__global__ __launch_bounds__(256) void k_gemm(const unsigned short* __restrict__ Ab,
                                              const unsigned short* __restrict__ Bp,
                                              const float* __restrict__ bl0,
                                              const float* __restrict__ Wl1,
                                              const float* __restrict__ Wr1,
                                              float* __restrict__ g,
                                              float* __restrict__ r) {
    __shared__ float4 Bs[2048];          // 32 KB: one K-quarter of packed B
    __shared__ float wl1s[HC][3];
    __shared__ float wr1s[HC][3];
    __shared__ float bls[HC];

    int t = threadIdx.x;
    for (int i = t; i < HC * 3; i += 256) {
        wl1s[i / 3][i % 3] = Wl1[i];
        wr1s[i / 3][i % 3] = Wr1[i];
    }
    for (int i = t; i < HC; i += 256) bls[i] = bl0[i];

    int w = t >> 6, l = t & 63;
    int n0 = blockIdx.x * 128 + w * 32;  // wave owns rows n0..n0+31 (two 16-row D tiles)

    f32x4 acc0[16], acc1[16];
    #pragma unroll
    for (int i = 0; i < 16; ++i) { acc0[i] = (f32x4){0.f,0.f,0.f,0.f}; acc1[i] = (f32x4){0.f,0.f,0.f,0.f}; }

    // A-frags for both row tiles; prefetch all upfront (L3 latency under first stage+barrier)
    const short8* A8a = (const short8*)Ab + ((size_t)(n0 + (l & 15)) * 32 + (l >> 4));
    const short8* A8b = A8a + 16 * 32;
    short8 afr0[8], afr1[8];
    #pragma unroll
    for (int kt = 0; kt < 8; ++kt) { afr0[kt] = A8a[kt * 4]; afr1[kt] = A8b[kt * 4]; }

    for (int q = 0; q < 4; ++q) {
        __syncthreads();
        const float4* gsrc = (const float4*)(Bp + (size_t)q * 16384);  // 32KB quarter
        #pragma unroll
        for (int i = 0; i < 8; ++i)
            Bs[i * 256 + t] = gsrc[i * 256 + t];
        __syncthreads();
        #pragma unroll
        for (int j = 0; j < 2; ++j) {
            int kt = q * 2 + j;
            const short8* B8 = (const short8*)Bs + (j * 1024 + l);
            #pragma unroll
            for (int nt = 0; nt < 16; ++nt) {
                short8 bf = B8[nt * 64];
                acc0[nt] = __builtin_amdgcn_mfma_f32_16x16x32_bf16(afr0[kt], bf, acc0[nt], 0, 0, 0);
                acc1[nt] = __builtin_amdgcn_mfma_f32_16x16x32_bf16(afr1[kt], bf, acc1[nt], 0, 0, 0);
            }
        }
    }

    // epilogue x2: D lane l reg e = H[row=(l>>4)*4+e][col=nt*16+(l&15)]
    #pragma unroll
    for (int half = 0; half < 2; ++half) {
        float pl[4][3] = {{0.f}}, pr[4][3] = {{0.f}};
        #pragma unroll
        for (int nt = 0; nt < 16; ++nt) {
            int col = nt * 16 + (l & 15);
            float b = bls[col];
            #pragma unroll
            for (int e = 0; e < 4; ++e) {
                float h = fmaxf((half ? acc1[nt][e] : acc0[nt][e]) + b, 0.0f);
                #pragma unroll
                for (int j = 0; j < 3; ++j) {
                    pl[e][j] = fmaf(h, wl1s[col][j], pl[e][j]);
                    pr[e][j] = fmaf(h, wr1s[col][j], pr[e][j]);
                }
            }
        }
        #pragma unroll
        for (int m = 1; m <= 8; m <<= 1) {
            #pragma unroll
            for (int e = 0; e < 4; ++e)
                #pragma unroll
                for (int j = 0; j < 3; ++j) {
                    pl[e][j] += __shfl_xor(pl[e][j], m);
                    pr[e][j] += __shfl_xor(pr[e][j], m);
                }
        }
        if ((l & 15) == 0) {
            #pragma unroll
            for (int e = 0; e < 4; ++e) {
                int node = n0 + half * 16 + (l >> 4) * 4 + e;
                if (node < NN) {
                    #pragma unroll
                    for (int j = 0; j < 3; ++j) {
                        g[node * 3 + j] = pl[e][j];
                        r[node * 3 + j] = pr[e][j];
                    }
                }
            }
        }
    }
}

// ---------------- fused layer-1 aggregation by GATHER + final output ----------------
__global__ __launch_bounds__(256) void k_out(const int* __restrict__ degi,
                                             const unsigned short* __restrict__ csrp,
                                             const float* __restrict__ g,
                                             const float* __restrict__ r,
                                             const float* __restrict__ bl1,
                                             float* __restrict__ out) {
    int tid = blockIdx.x * 256 + threadIdx.x;
    int n = tid >> 3;
    int sl = tid & 7;
    if (n >= NN) return;
    int deg = min(degi[n << 4], PAD);
    int beg = n * PAD;
    float s0 = 0.f, s1 = 0.f, s2 = 0.f;
    for (int j = sl; j < deg; j += 8) {
        int src = csrp[beg + j];
        s0 += g[src * 3 + 0];
        s1 += g[src * 3 + 1];
        s2 += g[src * 3 + 2];
    }
    #pragma unroll
    for (int m = 1; m < 8; m <<= 1) {
        s0 += __shfl_xor(s0, m);
        s1 += __shfl_xor(s1, m);
        s2 += __shfl_xor(s2, m);
    }
    if (sl == 0) {
        float inv = 1.0f / fmaxf((float)deg, 1.0f);
        out[n * 3 + 0] = s0 * inv + bl1[0] + r[n * 3 + 0];
        out[n * 3 + 1] = s1 * inv + bl1[1] + r[n * 3 + 1];
        out[n * 3 + 2] = s2 * inv + bl1[2] + r[n * 3 + 2];
    }
}

extern "C" void kernel_launch(void* const* d_in, const int* in_sizes, int n_in,
                              void* d_out, int out_size, void* d_ws, size_t ws_size,
                              hipStream_t stream) {
    const float* x   = (const float*)d_in[0];
    const int*   ei  = (const int*)d_in[1];
    const float* Wl0 = (const float*)d_in[2];
    const float* bl0 = (const float*)d_in[3];
    const float* Wr0 = (const float*)d_in[4];
    const float* Wl1 = (const float*)d_in[5];
    const float* bl1 = (const float*)d_in[6];
    const float* Wr1 = (const float*)d_in[7];
    float* out = (float*)d_out;

    char* ws = (char*)d_ws;
    int*            degi = (int*)(ws);                        //  3,200,064 (NN*16 ints, 1 counter / 64B line)
    unsigned short* csrp = (unsigned short*)(ws + 3200064);   //  6,400,000 (NN*PAD*2)
    unsigned short* Ab   = (unsigned short*)(ws + 9600064);   // 25,624,576 (NNP*256*2)
    unsigned short* Bp   = (unsigned short*)(ws + 35224640);  //    131,072
    float*          g    = (float*)(ws + 35355712);           //    600,064
    float*          r    = (float*)(ws + 35955776);           //    600,064  -> ~36.6 MB

    k_prep <<<TOBF16_BLOCKS + WPACK_BLOCKS + DEGZ_BLOCKS, 256, 0, stream>>>(x, Wl0, Wr0, Ab, Bp, degi);
    k_build<<<(NE + 255) / 256, 256, 0, stream>>>(ei, degi, csrp);
    k_agg  <<<(NN * 64 + 255) / 256, 256, 0, stream>>>(degi, csrp, Ab);
    k_gemm <<<NNP / 128, 256, 0, stream>>>(Ab, Bp, bl0, Wl1, Wr1, g, r);
    k_out  <<<(NN * 8 + 255) / 256, 256, 0, stream>>>(degi, csrp, g, r, bl1, out);
}

// Round 15
// 105.073 us; speedup vs baseline: 1.6855x; 1.6855x over previous
//
#include <hip/hip_runtime.h>

#define NN 50000
#define NNP 50048   // Ab rows padded to multiple of 64
#define NE 640000
#define IC 128
#define HC 256
#define OC 3
#define PAD 64      // padded CSR row capacity; P(deg>=64)~1e-25 for Poisson(12.8); guarded anyway

#define TOBF16_BLOCKS (NN * IC / 4 / 256)          // 6250
#define WPACK_BLOCKS  32
#define DEGZ_BLOCKS   ((NN * 16 / 4 + 255) / 256)  // 782: zero NN*16 ints as uint4

typedef __attribute__((ext_vector_type(8))) short short8;
typedef __attribute__((ext_vector_type(4))) float f32x4;

__device__ __forceinline__ unsigned short f2bf(float f) {   // fp32 -> bf16 RNE
    unsigned int u = __float_as_uint(f);
    unsigned int r = u + 0x7FFFu + ((u >> 16) & 1u);
    return (unsigned short)(r >> 16);
}
__device__ __forceinline__ float bflo(unsigned int v) { return __uint_as_float(v << 16); }
__device__ __forceinline__ float bfhi(unsigned int v) { return __uint_as_float(v & 0xffff0000u); }

// ---------------- prep: zero spread-degi | x->bf16 | pack W ----------------
__global__ __launch_bounds__(256) void k_prep(const float* __restrict__ x,
                                              const float* __restrict__ Wl0,
                                              const float* __restrict__ Wr0,
                                              unsigned short* __restrict__ Ab,
                                              unsigned short* __restrict__ Bp,
                                              int* __restrict__ degi) {
    int b = blockIdx.x;
    int t = threadIdx.x;
    if (b < TOBF16_BLOCKS) {
        // x -> bf16 into right half of Ab (Ab: ushort[NNP][256], cols 128..255 = x)
        int i = b * 256 + t;                  // over NN*IC/4 float4s
        int n = i >> 5;
        int c = (i & 31) * 4;
        float4 v = ((const float4*)x)[i];
        ushort4 o;
        o.x = f2bf(v.x); o.y = f2bf(v.y); o.z = f2bf(v.z); o.w = f2bf(v.w);
        *(ushort4*)&Ab[(size_t)n * 256 + 128 + c] = o;
    } else if (b < TOBF16_BLOCKS + WPACK_BLOCKS) {
        // pack [Wl0;Wr0] into MFMA B-fragment order:
        // Bp[kt(8)][nt(16)][lane(64)][e(8)], B[k][n]: k=kt*32+(lane>>4)*8+e, n=nt*16+(lane&15)
        int tt = (b - TOBF16_BLOCKS) * 256 + t;     // 8192 threads
        int l = tt & 63;
        int nt = (tt >> 6) & 15;
        int kt = tt >> 10;
        int n = nt * 16 + (l & 15);
        int kbase = kt * 32 + (l >> 4) * 8;
        unsigned short o[8];
        #pragma unroll
        for (int e = 0; e < 8; ++e) {
            int k = kbase + e;
            float w = (k < IC) ? Wl0[k * HC + n] : Wr0[(k - IC) * HC + n];
            o[e] = f2bf(w);
        }
        #pragma unroll
        for (int e = 0; e < 8; ++e) Bp[(size_t)tt * 8 + e] = o[e];
    } else {
        // zero spread degi: counter n lives at degi[n*16] (one per 64B line)
        int idx = (b - TOBF16_BLOCKS - WPACK_BLOCKS) * 256 + t;
        if (idx < NN * 16 / 4) ((uint4*)degi)[idx] = make_uint4(0u, 0u, 0u, 0u);
    }
}

// ---------------- one-pass padded-CSR build; line-isolated counters ----------------
__global__ __launch_bounds__(256) void k_build(const int* __restrict__ ei,
                                               int* __restrict__ degi,
                                               unsigned short* __restrict__ csrp) {
    int e = blockIdx.x * blockDim.x + threadIdx.x;
    if (e >= NE) return;
    int src = ei[e];
    int dst = ei[NE + e];
    int rank = atomicAdd(&degi[dst << 4], 1);   // stride-16: one counter per cache line
    if (rank < PAD) csrp[dst * PAD + rank] = (unsigned short)src;
}

// ---------------- gather-mean: 8 edge-subgroups x 8 lanes x 2 uint4 (32B/lane) ----------------
__global__ __launch_bounds__(256) void k_agg(const int* __restrict__ degi,
                                             const unsigned short* __restrict__ csrp,
                                             unsigned short* __restrict__ Ab) {
    int wid = (blockIdx.x * blockDim.x + threadIdx.x) >> 6;
    int lane = threadIdx.x & 63;
    if (wid >= NN) return;
    int deg = min(degi[wid << 4], PAD);
    int beg = wid * PAD;
    int sg = lane >> 3;        // edge subgroup 0..7 (8 edges in flight per wave)
    int s  = lane & 7;         // this lane covers uint4 slots s and s+8 of the x-half
    const uint4* base = (const uint4*)Ab;     // 32 uint4 per 512B row

    float a[16];
    #pragma unroll
    for (int i = 0; i < 16; ++i) a[i] = 0.f;

    for (int j = sg; j < deg; j += 8) {
        int src = csrp[beg + j];
        uint4 v0 = base[(size_t)src * 32 + 16 + s];
        uint4 v1 = base[(size_t)src * 32 + 24 + s];
        a[0] += bflo(v0.x); a[1] += bfhi(v0.x);
        a[2] += bflo(v0.y); a[3] += bfhi(v0.y);
        a[4] += bflo(v0.z); a[5] += bfhi(v0.z);
        a[6] += bflo(v0.w); a[7] += bfhi(v0.w);
        a[8]  += bflo(v1.x); a[9]  += bfhi(v1.x);
        a[10] += bflo(v1.y); a[11] += bfhi(v1.y);
        a[12] += bflo(v1.z); a[13] += bfhi(v1.z);
        a[14] += bflo(v1.w); a[15] += bfhi(v1.w);
    }
    #pragma unroll
    for (int m = 8; m <= 32; m <<= 1)
        #pragma unroll
        for (int i = 0; i < 16; ++i) a[i] += __shfl_xor(a[i], m);

    if (sg == 0) {
        float inv = 1.0f / fmaxf((float)deg, 1.0f);
        uint4 o0, o1;
        o0.x = ((unsigned int)f2bf(a[1] * inv) << 16) | f2bf(a[0] * inv);
        o0.y = ((unsigned int)f2bf(a[3] * inv) << 16) | f2bf(a[2] * inv);
        o0.z = ((unsigned int)f2bf(a[5] * inv) << 16) | f2bf(a[4] * inv);
        o0.w = ((unsigned int)f2bf(a[7] * inv) << 16) | f2bf(a[6] * inv);
        o1.x = ((unsigned int)f2bf(a[9]  * inv) << 16) | f2bf(a[8]  * inv);
        o1.y = ((unsigned int)f2bf(a[11] * inv) << 16) | f2bf(a[10] * inv);
        o1.z = ((unsigned int)f2bf(a[13] * inv) << 16) | f2bf(a[12] * inv);
        o1.w = ((unsigned int)f2bf(a[15] * inv) << 16) | f2bf(a[14] * inv);
        ((uint4*)Ab)[(size_t)wid * 32 + s] = o0;
        ((uint4*)Ab)[(size_t)wid * 32 + 8 + s] = o1;
    }
}

// ---------------- MFMA GEMM v5: v3 structure, VGPR-capped for 4 waves/SIMD ----------------
// 16 rows/wave, 64 rows/block, 782 blocks. Per-quarter A loads (2 frags) issued
// before the staging barriers so their latency hides under stage+barrier.
// H = relu(Ab @ [Wl0;Wr0] + bl0); g = H@Wl1; r = H@Wr1
__global__ __launch_bounds__(256, 4) void k_gemm(const unsigned short* __restrict__ Ab,
                                                 const unsigned short* __restrict__ Bp,
                                                 const float* __restrict__ bl0,
                                                 const float* __restrict__ Wl1,
                                                 const float* __restrict__ Wr1,
                                                 float* __restrict__ g,
                                                 float* __restrict__ r) {
    __shared__ float4 Bs[2048];          // 32 KB: one K-quarter of packed B
    __shared__ float wl1s[HC][3];
    __shared__ float wr1s[HC][3];
    __shared__ float bls[HC];

    int t = threadIdx.x;
    for (int i = t; i < HC * 3; i += 256) {
        wl1s[i / 3][i % 3] = Wl1[i];
        wr1s[i / 3][i % 3] = Wr1[i];
    }
    for (int i = t; i < HC; i += 256) bls[i] = bl0[i];

    int w = t >> 6, l = t & 63;
    int n0 = blockIdx.x * 64 + w * 16;

    f32x4 acc[16];
    #pragma unroll
    for (int i = 0; i < 16; ++i) acc[i] = (f32x4){0.f, 0.f, 0.f, 0.f};

    // A-frag: lane l supplies A[n0 + (l&15)][kt*32 + (l>>4)*8 + e]
    const short8* A8 = (const short8*)Ab + ((size_t)(n0 + (l & 15)) * 32 + (l >> 4));

    for (int q = 0; q < 4; ++q) {
        // issue this quarter's two A fragments first: latency hides under stage+barrier
        short8 af0 = A8[(q * 2 + 0) * 4];
        short8 af1 = A8[(q * 2 + 1) * 4];
        __syncthreads();
        const float4* gsrc = (const float4*)(Bp + (size_t)q * 16384);  // 32KB quarter
        #pragma unroll
        for (int i = 0; i < 8; ++i)
            Bs[i * 256 + t] = gsrc[i * 256 + t];
        __syncthreads();
        const short8* B8 = (const short8*)Bs + l;
        #pragma unroll
        for (int nt = 0; nt < 16; ++nt) {
            short8 bf = B8[nt * 64];
            acc[nt] = __builtin_amdgcn_mfma_f32_16x16x32_bf16(af0, bf, acc[nt], 0, 0, 0);
        }
        B8 = (const short8*)Bs + (1024 + l);
        #pragma unroll
        for (int nt = 0; nt < 16; ++nt) {
            short8 bf = B8[nt * 64];
            acc[nt] = __builtin_amdgcn_mfma_f32_16x16x32_bf16(af1, bf, acc[nt], 0, 0, 0);
        }
    }

    // epilogue: D lane l reg e = H[row=(l>>4)*4+e][col=nt*16+(l&15)]
    float pl[4][3] = {{0.f}}, pr[4][3] = {{0.f}};
    #pragma unroll
    for (int nt = 0; nt < 16; ++nt) {
        int col = nt * 16 + (l & 15);
        float b = bls[col];
        #pragma unroll
        for (int e = 0; e < 4; ++e) {
            float h = fmaxf(acc[nt][e] + b, 0.0f);
            #pragma unroll
            for (int j = 0; j < 3; ++j) {
                pl[e][j] = fmaf(h, wl1s[col][j], pl[e][j]);
                pr[e][j] = fmaf(h, wr1s[col][j], pr[e][j]);
            }
        }
    }
    #pragma unroll
    for (int m = 1; m <= 8; m <<= 1) {
        #pragma unroll
        for (int e = 0; e < 4; ++e)
            #pragma unroll
            for (int j = 0; j < 3; ++j) {
                pl[e][j] += __shfl_xor(pl[e][j], m);
                pr[e][j] += __shfl_xor(pr[e][j], m);
            }
    }
    if ((l & 15) == 0) {
        #pragma unroll
        for (int e = 0; e < 4; ++e) {
            int node = n0 + (l >> 4) * 4 + e;
            if (node < NN) {
                #pragma unroll
                for (int j = 0; j < 3; ++j) {
                    g[node * 3 + j] = pl[e][j];
                    r[node * 3 + j] = pr[e][j];
                }
            }
        }
    }
}

// ---------------- fused layer-1 aggregation by GATHER + final output ----------------
__global__ __launch_bounds__(256) void k_out(const int* __restrict__ degi,
                                             const unsigned short* __restrict__ csrp,
                                             const float* __restrict__ g,
                                             const float* __restrict__ r,
                                             const float* __restrict__ bl1,
                                             float* __restrict__ out) {
    int tid = blockIdx.x * 256 + threadIdx.x;
    int n = tid >> 3;
    int sl = tid & 7;
    if (n >= NN) return;
    int deg = min(degi[n << 4], PAD);
    int beg = n * PAD;
    float s0 = 0.f, s1 = 0.f, s2 = 0.f;
    for (int j = sl; j < deg; j += 8) {
        int src = csrp[beg + j];
        s0 += g[src * 3 + 0];
        s1 += g[src * 3 + 1];
        s2 += g[src * 3 + 2];
    }
    #pragma unroll
    for (int m = 1; m < 8; m <<= 1) {
        s0 += __shfl_xor(s0, m);
        s1 += __shfl_xor(s1, m);
        s2 += __shfl_xor(s2, m);
    }
    if (sl == 0) {
        float inv = 1.0f / fmaxf((float)deg, 1.0f);
        out[n * 3 + 0] = s0 * inv + bl1[0] + r[n * 3 + 0];
        out[n * 3 + 1] = s1 * inv + bl1[1] + r[n * 3 + 1];
        out[n * 3 + 2] = s2 * inv + bl1[2] + r[n * 3 + 2];
    }
}

extern "C" void kernel_launch(void* const* d_in, const int* in_sizes, int n_in,
                              void* d_out, int out_size, void* d_ws, size_t ws_size,
                              hipStream_t stream) {
    const float* x   = (const float*)d_in[0];
    const int*   ei  = (const int*)d_in[1];
    const float* Wl0 = (const float*)d_in[2];
    const float* bl0 = (const float*)d_in[3];
    const float* Wr0 = (const float*)d_in[4];
    const float* Wl1 = (const float*)d_in[5];
    const float* bl1 = (const float*)d_in[6];
    const float* Wr1 = (const float*)d_in[7];
    float* out = (float*)d_out;

    char* ws = (char*)d_ws;
    int*            degi = (int*)(ws);                        //  3,200,064 (NN*16 ints, 1 counter / 64B line)
    unsigned short* csrp = (unsigned short*)(ws + 3200064);   //  6,400,000 (NN*PAD*2)
    unsigned short* Ab   = (unsigned short*)(ws + 9600064);   // 25,624,576 (NNP*256*2)
    unsigned short* Bp   = (unsigned short*)(ws + 35224640);  //    131,072
    float*          g    = (float*)(ws + 35355712);           //    600,064
    float*          r    = (float*)(ws + 35955776);           //    600,064  -> ~36.6 MB

    k_prep <<<TOBF16_BLOCKS + WPACK_BLOCKS + DEGZ_BLOCKS, 256, 0, stream>>>(x, Wl0, Wr0, Ab, Bp, degi);
    k_build<<<(NE + 255) / 256, 256, 0, stream>>>(ei, degi, csrp);
    k_agg  <<<(NN * 64 + 255) / 256, 256, 0, stream>>>(degi, csrp, Ab);
    k_gemm <<<(NN + 63) / 64, 256, 0, stream>>>(Ab, Bp, bl0, Wl1, Wr1, g, r);
    k_out  <<<(NN * 8 + 255) / 256, 256, 0, stream>>>(degi, csrp, g, r, bl1, out);
}